// Round 12
// baseline (583.150 us; speedup 1.0000x reference)
//
#include <hip/hip_runtime.h>
#include <hip/hip_bf16.h>
#include <math.h>

#define E_EDGES 50000
#define NN 5000

typedef __hip_bfloat16 bf16;
typedef __attribute__((ext_vector_type(8))) short short8;
typedef __attribute__((ext_vector_type(4))) float f32x4;

__device__ __forceinline__ float b2f(bf16 v) { return __bfloat162float(v); }
__device__ __forceinline__ float siluf(float x) { return x / (1.0f + __expf(-x)); }
__device__ __forceinline__ float us2f(unsigned short u) {
  union { unsigned int i; float f; } c; c.i = ((unsigned int)u) << 16; return c.f;
}

// ================= merged setup: prep(+hist) | fuse->Mbb | embed | w0rtb | w2t =================
__global__ void __launch_bounds__(256) k_setup(
    const float* __restrict__ evec, const float* __restrict__ elen,
    float* __restrict__ shb, float* __restrict__ bc,
    const float* __restrict__ w2, const float* __restrict__ b2,
    const float* __restrict__ w01, const float* __restrict__ w11,
    bf16* __restrict__ Mbb,
    float* __restrict__ bias0, float* __restrict__ bias1,
    const float* __restrict__ emb, const int* __restrict__ an,
    float* __restrict__ node0, bf16* __restrict__ node0b,
    const float* __restrict__ w0, bf16* __restrict__ W0rtb,
    const float* __restrict__ w1w2, bf16* __restrict__ W2t,
    const int* __restrict__ ei, int* __restrict__ hist) {
  const int b = blockIdx.x, tid = threadIdx.x;
  if (b < 196) {                      // ---- prep (sh + basis*cutoff) + src histogram
    int e = b*256 + tid;
    if (e >= E_EDGES) return;
    atomicAdd(&hist[ei[e]], 1);
    float x = evec[3*e+0], y = evec[3*e+1], z = evec[3*e+2];
    float r = elen[e];
    float inv = 1.0f / (r + 1e-8f);
    float ux = x*inv, uy = y*inv, uz = z*inv;
    const float s3 = 1.7320508075688772f, s5 = 2.2360679774997896f, s15 = 3.8729833462074170f;
    float* sh = shb + (size_t)e*12;
    sh[0] = 1.0f;
    sh[1] = s3*uy; sh[2] = s3*uz; sh[3] = s3*ux;
    sh[4] = s15*ux*uy; sh[5] = s15*uy*uz; sh[6] = 0.5f*s5*(3.0f*uz*uz - 1.0f);
    sh[7] = s15*ux*uz; sh[8] = 0.5f*s15*(ux*ux - uy*uy);
    sh[9] = 0.f; sh[10] = 0.f; sh[11] = 0.f;
    float rr = fmaxf(r, 1e-8f);
    const float pi = 3.14159265358979f;
    float xr = r * 0.2f;
    float cut = (xr < 1.0f) ? 0.5f*(1.0f + cosf(pi*xr)) : 0.0f;
    float fb = pi * 0.2f;
    for (int k = 1; k <= 8; ++k)
      bc[(size_t)e*8 + (k-1)] = sinf(fb*(float)k*r)/rr * cut;
  } else if (b < 212) {               // ---- fuse rad_w2 into wnn*_w1 -> Mbb (B-layout bf16)
    int i = (b-196)*256 + tid;        // 4096
    int hh = i >> 6, c = i & 63;
    float a0 = 0.f, a1 = 0.f;
    for (int j = 0; j < 64; ++j) {
      float wv = w2[hh*64 + j];
      a0 += wv * w01[j*64 + c];
      a1 += wv * w11[j*64 + c];
    }
    Mbb[(size_t)c*64 + hh]        = __float2bfloat16(a0);
    Mbb[(size_t)(64 + c)*64 + hh] = __float2bfloat16(a1);
    if (hh == 0) {
      float s0 = 0.f, s1 = 0.f;
      for (int j = 0; j < 64; ++j) {
        s0 += b2[j] * w01[j*64 + c];
        s1 += b2[j] * w11[j*64 + c];
      }
      bias0[c] = s0;
      bias1[c] = s1;
    }
  } else if (b < 1462) {              // ---- embed (320000 exact): fp32 + bf16 copies
    int i = (b-212)*256 + tid;
    int n = i >> 6, c = i & 63;
    float v = emb[an[n]*64 + c];
    node0[i] = v;
    node0b[i] = __float2bfloat16(v);
  } else if (b < 2358) {              // ---- W0rtb[col*64+u] bf16, col = h*56+vp (229376 exact)
    int idx = (b-1462)*256 + tid;
    int col = idx >> 6, u = idx & 63;
    int hh = col / 56, vp = col - hh*56;
    int boff, m3, v;
    if (vp < 32)      { boff = 0;    m3 = 32; v = vp; }
    else if (vp < 48) { boff = 2048; m3 = 16; v = vp - 32; }
    else              { boff = 3072; m3 = 8;  v = vp - 48; }
    W0rtb[idx] = __float2bfloat16(w0[hh*3584 + boff + u*m3 + v]);
  } else {                            // ---- w2t transpose + per-path [v][u] permute
    int idx = (b-2358)*256 + tid;     // 221184 exact
    int nn = idx >> 6, k = idx & 63;
    int p, loc;
    if (nn < 1024)      { p=0;  loc=nn;      }
    else if (nn < 1536) { p=1;  loc=nn-1024; }
    else if (nn < 1792) { p=2;  loc=nn-1536; }
    else if (nn < 2048) { p=3;  loc=nn-1792; }
    else if (nn < 2560) { p=4;  loc=nn-2048; }
    else if (nn < 2688) { p=5;  loc=nn-2560; }
    else if (nn < 2944) { p=6;  loc=nn-2688; }
    else if (nn < 3008) { p=7;  loc=nn-2944; }
    else if (nn < 3136) { p=8;  loc=nn-3008; }
    else if (nn < 3392) { p=9;  loc=nn-3136; }
    else                { p=10; loc=nn-3392; }
    const int M1s[11] = {32,32,32,16,16,16,16,8,8,8,8};
    const int M3s[11] = {32,16,8,16,32,8,16,8,16,32,8};
    int m1 = M1s[p], m3 = M3s[p];
    int v = loc / m1, u = loc - v*m1;
    int src = (nn - loc) + u*m3 + v;
    W2t[idx] = __float2bfloat16(w1w2[(size_t)k*3456 + src]);
  }
}

// ================= k_mid: rad (h-VALU + MFMA q-GEMM) | scan =================
__global__ void __launch_bounds__(256) k_mid(
    const float* __restrict__ bc,
    const float* __restrict__ w1, const float* __restrict__ b1,
    const bf16* __restrict__ Mbb,
    const float* __restrict__ bias0, const float* __restrict__ bias1,
    float* __restrict__ q0, bf16* __restrict__ q1b,
    const int* __restrict__ hist, int* __restrict__ start) {
  __shared__ float smem[1024];
  __shared__ __align__(16) short sHb[2048];
  const int tid = threadIdx.x;
  const int b = blockIdx.x;
  if (b < 1563) {
    float* sW1 = smem;
    float* sB  = smem + 512;
    float* sb0 = smem + 576;
    float* sb1 = smem + 640;
    float* sBC = smem + 704;
    const int j = tid >> 6, m = tid & 63;
    for (int i = tid; i < 512; i += 256) sW1[i] = w1[i];
    if (tid < 64) { sB[tid] = b1[tid]; sb0[tid] = bias0[tid]; sb1[tid] = bias1[tid]; }
    {
      int e = b*32 + (tid >> 3);
      int k = tid & 7;
      int eL = e < E_EDGES ? e : E_EDGES-1;
      sBC[tid] = bc[(size_t)eL*8 + k];
    }
    __syncthreads();
    #pragma unroll
    for (int g = 0; g < 8; ++g) {
      int el = g*4 + j;
      float t = sB[m];
      #pragma unroll
      for (int k = 0; k < 8; ++k) t += sBC[el*8+k]*sW1[k*64+m];
      bf16 hv = __float2bfloat16(siluf(t));
      sHb[el*64 + m] = *(short*)&hv;
    }
    __syncthreads();
    const int w = tid >> 6, lane = tid & 63;
    const int row16 = lane & 15, quad = lane >> 4;
    const int mtile = w & 1, cg = w >> 1;
    const short* ap = sHb + (mtile*16 + row16)*64 + quad*8;
    short8 a0 = *(const short8*)ap;
    short8 a1 = *(const short8*)(ap + 32);
    f32x4 acc[4] = {};
    #pragma unroll
    for (int ni = 0; ni < 4; ++ni) {
      const short* bp = (const short*)Mbb + (size_t)(cg*64 + ni*16 + row16)*64 + quad*8;
      short8 b0 = *(const short8*)bp;
      short8 b1v = *(const short8*)(bp + 32);
      acc[ni] = __builtin_amdgcn_mfma_f32_16x16x32_bf16(a0, b0, acc[ni], 0,0,0);
      acc[ni] = __builtin_amdgcn_mfma_f32_16x16x32_bf16(a1, b1v, acc[ni], 0,0,0);
    }
    const float* bias = cg ? sb1 : sb0;
    #pragma unroll
    for (int ni = 0; ni < 4; ++ni) {
      int c = ni*16 + row16;
      float bv = bias[c];
      #pragma unroll
      for (int r = 0; r < 4; ++r) {
        int e = b*32 + mtile*16 + quad*4 + r;
        if (e < E_EDGES) {
          float val = siluf(acc[ni][r] + bv);
          if (cg == 0) q0[(size_t)e*64 + c] = val;
          else         q1b[(size_t)e*64 + c] = __float2bfloat16(val);
        }
      }
    }
  } else {
    int* sp = (int*)smem;
    int base = tid*20;
    int localsum = 0;
    for (int i = 0; i < 20; ++i) { int jj = base+i; localsum += (jj < NN) ? hist[jj] : 0; }
    sp[tid] = localsum;
    __syncthreads();
    if (tid == 0) {
      int acc = 0;
      for (int i = 0; i < 256; ++i) { int t = sp[i]; sp[i] = acc; acc += t; }
    }
    __syncthreads();
    int run = sp[tid];
    for (int i = 0; i < 20; ++i) {
      int jj = base+i;
      if (jj < NN) { start[jj] = run; run += hist[jj]; }
    }
    if (tid == 255) start[NN] = run;
  }
}

// ================= generic MFMA GEMM: out[r, :] = A[r, :64] @ B([col][64k]) =================
__global__ void __launch_bounds__(256) k_bgemm(
    const bf16* __restrict__ A, const bf16* __restrict__ B,
    bf16* __restrict__ out, int stride, int ntiles, int e0, int nE) {
  __shared__ short lds[4][32*64];
  const int tid = threadIdx.x;
  const int wid = tid >> 6, lane = tid & 63;
  const int nt = blockIdx.x*4 + wid;
  const int r0 = blockIdx.y*32;
  const int row16 = lane & 15, quad = lane >> 4;

  short8 a[2][2];
  #pragma unroll
  for (int mi = 0; mi < 2; ++mi) {
    int r = r0 + mi*16 + row16;
    int rg = e0 + ((r < nE) ? r : 0);
    const short* ap = (const short*)A + (size_t)rg*64 + quad*8;
    a[mi][0] = *(const short8*)(ap);
    a[mi][1] = *(const short8*)(ap + 32);
  }
  if (nt < ntiles) {
    f32x4 acc[4][2] = {};
    #pragma unroll
    for (int ni = 0; ni < 4; ++ni) {
      int col = nt*64 + ni*16 + row16;
      const short* bp = (const short*)B + (size_t)col*64 + quad*8;
      short8 b0 = *(const short8*)(bp);
      short8 b1 = *(const short8*)(bp + 32);
      #pragma unroll
      for (int mi = 0; mi < 2; ++mi) {
        acc[ni][mi] = __builtin_amdgcn_mfma_f32_16x16x32_bf16(a[mi][0], b0, acc[ni][mi], 0,0,0);
        acc[ni][mi] = __builtin_amdgcn_mfma_f32_16x16x32_bf16(a[mi][1], b1, acc[ni][mi], 0,0,0);
      }
    }
    #pragma unroll
    for (int ni = 0; ni < 4; ++ni)
      #pragma unroll
      for (int mi = 0; mi < 2; ++mi)
        #pragma unroll
        for (int rr = 0; rr < 4; ++rr) {
          bf16 hv = __float2bfloat16(acc[ni][mi][rr]);
          lds[wid][(mi*16 + quad*4 + rr)*64 + ni*16 + row16] = *(short*)&hv;
        }
  }
  __syncthreads();
  if (nt < ntiles) {
    #pragma unroll
    for (int it = 0; it < 4; ++it) {
      int unit = it*64 + lane;
      int rrow = unit >> 3;
      int cu = (unit & 7) * 8;
      int r = r0 + rrow;
      if (r < nE)
        *(uint4*)((short*)out + (size_t)r*stride + nt*64 + cu) =
            *(const uint4*)&lds[wid][rrow*64 + cu];
    }
  }
}

// ================= CSR scatter: perm = edges sorted by src =================
__global__ void k_scat(const int* __restrict__ ei, const int* __restrict__ start,
                       int* __restrict__ cursor, int* __restrict__ perm) {
  int e = blockIdx.x*256 + threadIdx.x;
  if (e >= E_EDGES) return;
  int src = ei[e];
  int pos = start[src] + atomicAdd(&cursor[src], 1);
  perm[pos] = e;
}

// ================= layer-0 message: per-node; G0 row staged in LDS once =================
__global__ void __launch_bounds__(256) k_msg0c(
    const float* __restrict__ q0, const bf16* __restrict__ G0,
    const float* __restrict__ shb, const int* __restrict__ ei,
    const int* __restrict__ start, const int* __restrict__ perm,
    float* __restrict__ agg0) {
  __shared__ uint4 g4[448];
  __shared__ float sq[4][64];
  const int n = blockIdx.x;
  const int tid = threadIdx.x;
  const int wv = tid >> 6, lane = tid & 63;
  const uint4* gr = (const uint4*)(G0 + (size_t)n*3584);
  for (int i = tid; i < 448; i += 256) g4[i] = gr[i];
  const int s0 = start[n], s1 = start[n+1];
  __syncthreads();
  const short* gs = (const short*)g4;
  const float c = 0.125f * 0.3162277660168379f;
  for (int base = s0; base < s1; base += 4) {
    int idx = base + wv;
    if (idx < s1) {
      int e = perm[idx];
      sq[wv][lane] = q0[(size_t)e*64 + lane];
      float z = 0.f;
      if (lane < 56) {
        #pragma unroll
        for (int h = 0; h < 64; ++h)
          z += sq[wv][h]*us2f((unsigned short)gs[h*56 + lane]);
      }
      int dst = ei[E_EDGES + e];
      float* ap = agg0 + (size_t)dst*120;
      const float* sh = shb + (size_t)e*12;
      if (lane < 32) {
        atomicAdd(ap + lane, z*c);
      } else if (lane < 48) {
        int v = lane - 32;
        #pragma unroll
        for (int k = 0; k < 3; ++k) atomicAdd(ap + 32 + v*3 + k, z*sh[1+k]*c);
      } else if (lane < 56) {
        int v = lane - 48;
        #pragma unroll
        for (int k = 0; k < 5; ++k) atomicAdd(ap + 80 + v*5 + k, z*sh[4+k]*c);
      }
    }
  }
}

__global__ void k_node1(const float* __restrict__ agg0, const float* __restrict__ node0,
                        const float* __restrict__ sc00, float* __restrict__ node1) {
  __shared__ float n0[64];
  int n = blockIdx.x, tid = threadIdx.x;
  if (tid < 64) n0[tid] = node0[(size_t)n*64 + tid];
  __syncthreads();
  if (tid >= 120) return;
  float v = agg0[(size_t)n*120 + tid];
  if (tid < 32) {
    float s = 0.f;
    for (int u = 0; u < 64; ++u) s += n0[u]*sc00[u*32 + tid];
    v += s * 0.125f;
    v = siluf(v);
  }
  node1[(size_t)n*120 + tid] = v;
}

// ================= layer-1 consume: one wave/edge; w via global short8; reg accum =================
__global__ void __launch_bounds__(256) k_tp4(
    const bf16* __restrict__ wch, const float* __restrict__ node1,
    const float* __restrict__ shb, const int* __restrict__ ei,
    int e0, int nE, float* __restrict__ agg1) {
  __shared__ float tl[4][592];
  __shared__ float xl[4][120];
  __shared__ float shl[4][12];
  const int tid = threadIdx.x;
  const int wv = tid >> 6, lane = tid & 63;
  int elr = blockIdx.x*4 + wv;
  const bool live = elr < nE;
  const int el = live ? elr : nE-1;
  const int eg = e0 + el;
  const int src = ei[eg], dst = ei[E_EDGES + eg];

  for (int i = lane; i < 120; i += 64) xl[wv][i] = node1[(size_t)src*120 + i];
  if (lane < 12) shl[wv][lane] = shb[(size_t)eg*12 + lane];
  __syncthreads();

  {
    const float* x  = xl[wv];
    const float* sh = shl[wv];
    const float A = 0.3162277660168379f, Bc = 0.1825741858350554f, B2 = 0.3651483716701107f;
    const int I_[11] = {0,2,0,1,1,2, 0,1,2, 0,2};
    const int J_[11] = {2,0,1,0,2,1, 0,1,2, 0,2};
    const int K_[11] = {0,0,1,1,3,3, 2,2,2, 4,4};
    const float V_[11] = {A,A,A,A,A,A, -Bc,B2,-Bc, -A,A};
    for (int idx = lane; idx < 592; idx += 64) {
      float t = 0.0f;
      if (idx < 32)       { t = x[idx] * 0.1336306209562122f; }
      else if (idx < 128) { int j = idx-32,  u=j/3, k=j-u*3; t = x[u]*sh[1+k] * 0.1178511301977579f; }
      else if (idx < 288) { int j = idx-128, u=j/5, k=j-u*5; t = x[u]*sh[4+k] * 0.125f; }
      else if (idx < 336) { int j = idx-288, u=j/3, k=j-u*3; t = x[32+u*3+k] * 0.1178511301977579f; }
      else if (idx < 352) { int u = idx-336;
        t = (x[32+u*3]*sh[1] + x[32+u*3+1]*sh[2] + x[32+u*3+2]*sh[3]) * 0.0771516749810460f; }
      else if (idx < 432) { int j = idx-352, u=j/5, k=j-u*5;
        float s = 0.f;
        #pragma unroll
        for (int q = 0; q < 11; ++q) if (K_[q] == k)
          s += V_[q]*x[32+u*3+I_[q]]*sh[1+J_[q]];
        t = s * 0.2795084971874737f; }
      else if (idx < 480) { int j = idx-432, u=j/3, k=j-u*3;
        float s = 0.f;
        #pragma unroll
        for (int q = 0; q < 11; ++q) if (J_[q] == k)
          s += V_[q]*x[32+u*3+I_[q]]*sh[4+K_[q]];
        t = s * 0.2041241452319315f; }
      else if (idx < 520) { int j = idx-480, u=j/5, k=j-u*5; t = x[80+u*5+k] * 0.125f; }
      else if (idx < 544) { int j = idx-520, u=j/3, k=j-u*3;
        float s = 0.f;
        #pragma unroll
        for (int q = 0; q < 11; ++q) if (J_[q] == k)
          s += V_[q]*x[80+u*5+K_[q]]*sh[1+I_[q]];
        t = s * 0.2041241452319315f; }
      else if (idx < 552) { int u = idx-544;
        float s = 0.f;
        #pragma unroll
        for (int q = 0; q < 5; ++q) s += x[80+u*5+q]*sh[4+q];
        t = s * 0.0597614304667197f; }
      else { int j = idx-552, u=j/5, k=j-u*5;
        const float P = 0.2390457218668787f, Q = 0.2070196678027063f, R = 0.1195228609334394f;
        const int I2_[25] = {0,0,2, 0,0,1,1,3,3, 1,1,2, 1,1,4, 2, 2,3,3, 2,4,4, 3,3,4};
        const int J2_[25] = {0,2,0, 1,3,0,3,0,1, 1,2,1, 1,4,1, 2, 3,2,3, 4,2,4, 3,4,3};
        const int K2_[25] = {2,0,0, 3,1,3,0,1,0, 2,1,1, 4,1,1, 2, 3,3,2, 4,4,2, 4,3,3};
        const float V2_[25] = {P,P,P, -Q,-Q,-Q,-Q,-Q,-Q, -R,-R,-R, Q,Q,Q, -P,
                               -R,-R,-R, P,P,P, -Q,-Q,-Q};
        float s = 0.f;
        #pragma unroll
        for (int q = 0; q < 25; ++q) if (K2_[q] == k)
          s += V2_[q]*x[80+u*5+I2_[q]]*sh[4+J2_[q]];
        t = s * 0.2795084971874737f; }
      tl[wv][idx] = t;
    }
  }
  __syncthreads();

  const short* wrow = (const short*)wch + (size_t)el*3456;
  const float* t = tl[wv];
  float r0 = 0.f, r1 = 0.f, r2 = 0.f;
  #define PATHC(OFF, M1C, NKC, TOFFC, REG)                                  \
    { int v = lane / (NKC), k = lane - v*(NKC);                             \
      const short* wp = wrow + (OFF) + v*(M1C);                             \
      _Pragma("unroll")                                                     \
      for (int ub = 0; ub < (M1C)/8; ++ub) {                                \
        short8 w8 = *(const short8*)(wp + ub*8);                            \
        _Pragma("unroll")                                                   \
        for (int r = 0; r < 8; ++r)                                         \
          REG += us2f((unsigned short)w8[r]) * t[(TOFFC)+(ub*8+r)*(NKC)+k]; \
      } }
  if (lane < 32) {
    PATHC(0,    32, 1, 0,   r0)
    PATHC(2048, 16, 1, 336, r0)
    PATHC(3136,  8, 1, 544, r0)
  }
  if (lane < 48) {
    PATHC(1024, 32, 3, 32,  r1)
    PATHC(1792, 16, 3, 288, r1)
    PATHC(2688, 16, 3, 432, r1)
    PATHC(3008,  8, 3, 520, r1)
  }
  if (lane < 40) {
    PATHC(1536, 32, 5, 128, r2)
    PATHC(2560, 16, 5, 352, r2)
    PATHC(2944,  8, 5, 480, r2)
    PATHC(3392,  8, 5, 552, r2)
  }
  #undef PATHC

  if (live) {
    const float s = 0.3162277660168379f;
    float* ap = agg1 + (size_t)dst*120;
    if (lane < 32) atomicAdd(ap + lane, r0*s);
    if (lane < 48) atomicAdd(ap + 32 + lane, r1*s);
    if (lane < 40) atomicAdd(ap + 80 + lane, r2*s);
  }
}

__global__ void k_out(const float* __restrict__ agg1, const float* __restrict__ node1,
                      const float* __restrict__ sc0e, const float* __restrict__ sc1o,
                      const float* __restrict__ sc2e, float* __restrict__ out) {
  __shared__ float x[120];
  int n = blockIdx.x, tid = threadIdx.x;
  if (tid < 120) x[tid] = node1[(size_t)n*120 + tid];
  __syncthreads();
  if (tid >= 120) return;
  float v = agg1[(size_t)n*120 + tid];
  if (tid < 32) {
    float s = 0.f;
    for (int u = 0; u < 32; ++u) s += x[u]*sc0e[u*32 + tid];
    v += s * 0.1767766952966369f;
  } else if (tid < 80) {
    int jj = tid - 32, vv = jj/3, k = jj - vv*3;
    float s = 0.f;
    for (int u = 0; u < 16; ++u) s += x[32 + u*3 + k]*sc1o[u*16 + vv];
    v += s * 0.25f;
  } else {
    int jj = tid - 80, vv = jj/5, k = jj - vv*5;
    float s = 0.f;
    for (int u = 0; u < 8; ++u) s += x[80 + u*5 + k]*sc2e[u*8 + vv];
    v += s * 0.3535533905932738f;
  }
  out[(size_t)n*120 + tid] = v;
}

// ---------------- launch ----------------
extern "C" void kernel_launch(void* const* d_in, const int* in_sizes, int n_in,
                              void* d_out, int out_size, void* d_ws, size_t ws_size,
                              hipStream_t stream) {
  const float* embed   = (const float*)d_in[1];
  const float* rad_w1  = (const float*)d_in[2];
  const float* rad_b1  = (const float*)d_in[3];
  const float* rad_w2  = (const float*)d_in[4];
  const float* rad_b2  = (const float*)d_in[5];
  const float* wnn0_w1 = (const float*)d_in[6];
  const float* wnn0_w2 = (const float*)d_in[7];
  const float* wnn1_w1 = (const float*)d_in[8];
  const float* wnn1_w2 = (const float*)d_in[9];
  const float* sc0_0e  = (const float*)d_in[10];
  const float* sc1_0e  = (const float*)d_in[11];
  const float* sc1_1o  = (const float*)d_in[12];
  const float* sc1_2e  = (const float*)d_in[13];
  const float* edge_vec = (const float*)d_in[14];
  const float* edge_len = (const float*)d_in[15];
  const int*  anum    = (const int*)d_in[16];
  const int*  ei      = (const int*)d_in[17];

  float* ws = (float*)d_ws;
  float* shbuf = ws;                        // 600000
  float* bc    = ws + 600000;               // 400000
  bf16*  q1b   = (bf16*)(ws + 1000000);     // 1.6M f-slots
  float* node0 = ws + 2600000;              // 320000
  bf16*  node0b= (bf16*)(ws + 2920000);     // 160000 f-slots
  bf16*  W0rtb = (bf16*)(ws + 3080000);     // 114688 f-slots
  bf16*  W2t   = (bf16*)(ws + 3194688);     // 110592 f-slots
  bf16*  Mbb   = (bf16*)(ws + 3305280);     // 4096 f-slots
  float* bias0 = ws + 3309376;              // 64
  float* bias1 = ws + 3309440;              // 64
  float* agg0  = ws + 3309504;              // 600000
  float* agg1  = ws + 3909504;              // 600000
  int*   hist  = (int*)(ws + 4509504);      // 5000   (memset covers)
  int*   cursor= (int*)(ws + 4514504);      // 5000   (memset covers)
  int*   start = (int*)(ws + 4519504);      // 5008
  int*   perm  = (int*)(ws + 4524512);      // 50000
  float* node1 = ws + 4574512;              // 600000
  float* q0    = ws + 5174512;              // 3200000
  bf16*  G0    = (bf16*)(ws + 8374512);     // 8.96M f-slots -> base end 17334512 (69.3 MB)

  // layer-1 w buffer: CH=12500 (86.4 MB) keeps chunk + working set L3-resident
  long long CH; bf16* wbuf;
  const size_t base_end = 17334512ull;
  if      (ws_size >= (base_end + 21600000ull)*4) { CH = 12500; wbuf = (bf16*)(ws + base_end); }
  else                                            { CH = 6250;  wbuf = (bf16*)(ws + 5174512); } // alias q0+G0

  hipMemsetAsync(agg0, 0, 1210000*sizeof(float), stream);   // agg0+agg1+hist+cursor

  k_setup<<<3222, 256, 0, stream>>>(edge_vec, edge_len, shbuf, bc,
                                    rad_w2, rad_b2, wnn0_w1, wnn1_w1, Mbb, bias0, bias1,
                                    embed, anum, node0, node0b,
                                    wnn0_w2, W0rtb, wnn1_w2, W2t, ei, hist);
  k_mid<<<1564, 256, 0, stream>>>(bc, rad_w1, rad_b1, Mbb, bias0, bias1,
                                  q0, q1b, hist, start);
  k_bgemm<<<dim3(14, (NN+31)/32), 256, 0, stream>>>(node0b, W0rtb, G0, 3584, 56, 0, NN);
  k_scat<<<196, 256, 0, stream>>>(ei, start, cursor, perm);
  k_msg0c<<<NN, 256, 0, stream>>>(q0, G0, shbuf, ei, start, perm, agg0);
  k_node1<<<NN, 128, 0, stream>>>(agg0, node0, sc0_0e, node1);

  for (long long e0 = 0; e0 < E_EDGES; e0 += CH) {
    k_bgemm<<<dim3(14, (unsigned)((CH+31)/32), 1), 256, 0, stream>>>(q1b, W2t, wbuf, 3456, 54, (int)e0, (int)CH);
    k_tp4<<<(unsigned)((CH+3)/4), 256, 0, stream>>>(wbuf, node1, shbuf, ei, (int)e0, (int)CH, agg1);
  }
  k_out<<<NN, 128, 0, stream>>>(agg1, node1, sc1_0e, sc1_1o, sc1_2e, (float*)d_out);
}

// Round 14
// 501.218 us; speedup vs baseline: 1.1635x; 1.1635x over previous
//
#include <hip/hip_runtime.h>
#include <hip/hip_bf16.h>
#include <math.h>

#define E_EDGES 50000
#define NN 5000

typedef __hip_bfloat16 bf16;
typedef __attribute__((ext_vector_type(8))) short short8;
typedef __attribute__((ext_vector_type(4))) float f32x4;

__device__ __forceinline__ float b2f(bf16 v) { return __bfloat162float(v); }
__device__ __forceinline__ float siluf(float x) { return x / (1.0f + __expf(-x)); }
__device__ __forceinline__ float us2f(unsigned short u) {
  union { unsigned int i; float f; } c; c.i = ((unsigned int)u) << 16; return c.f;
}

// ================= merged setup: prep(+hists) | fuse->Mbb | embed | w0rtb | w2t =================
__global__ void __launch_bounds__(256) k_setup(
    const float* __restrict__ evec, const float* __restrict__ elen,
    float* __restrict__ shb, float* __restrict__ bc,
    const float* __restrict__ w2, const float* __restrict__ b2,
    const float* __restrict__ w01, const float* __restrict__ w11,
    bf16* __restrict__ Mbb,
    float* __restrict__ bias0, float* __restrict__ bias1,
    const float* __restrict__ emb, const int* __restrict__ an,
    float* __restrict__ node0, bf16* __restrict__ node0b,
    const float* __restrict__ w0, bf16* __restrict__ W0rtb,
    const float* __restrict__ w1w2, bf16* __restrict__ W2t,
    const int* __restrict__ ei, int* __restrict__ hist, int* __restrict__ hist2) {
  const int b = blockIdx.x, tid = threadIdx.x;
  if (b < 196) {                      // ---- prep (sh + basis*cutoff) + src/dst histograms
    int e = b*256 + tid;
    if (e >= E_EDGES) return;
    atomicAdd(&hist[ei[e]], 1);
    atomicAdd(&hist2[ei[E_EDGES + e]], 1);
    float x = evec[3*e+0], y = evec[3*e+1], z = evec[3*e+2];
    float r = elen[e];
    float inv = 1.0f / (r + 1e-8f);
    float ux = x*inv, uy = y*inv, uz = z*inv;
    const float s3 = 1.7320508075688772f, s5 = 2.2360679774997896f, s15 = 3.8729833462074170f;
    float* sh = shb + (size_t)e*12;
    sh[0] = 1.0f;
    sh[1] = s3*uy; sh[2] = s3*uz; sh[3] = s3*ux;
    sh[4] = s15*ux*uy; sh[5] = s15*uy*uz; sh[6] = 0.5f*s5*(3.0f*uz*uz - 1.0f);
    sh[7] = s15*ux*uz; sh[8] = 0.5f*s15*(ux*ux - uy*uy);
    sh[9] = 0.f; sh[10] = 0.f; sh[11] = 0.f;
    float rr = fmaxf(r, 1e-8f);
    const float pi = 3.14159265358979f;
    float xr = r * 0.2f;
    float cut = (xr < 1.0f) ? 0.5f*(1.0f + cosf(pi*xr)) : 0.0f;
    float fb = pi * 0.2f;
    for (int k = 1; k <= 8; ++k)
      bc[(size_t)e*8 + (k-1)] = sinf(fb*(float)k*r)/rr * cut;
  } else if (b < 212) {               // ---- fuse rad_w2 into wnn*_w1 -> Mbb (B-layout bf16)
    int i = (b-196)*256 + tid;        // 4096
    int hh = i >> 6, c = i & 63;
    float a0 = 0.f, a1 = 0.f;
    for (int j = 0; j < 64; ++j) {
      float wv = w2[hh*64 + j];
      a0 += wv * w01[j*64 + c];
      a1 += wv * w11[j*64 + c];
    }
    Mbb[(size_t)c*64 + hh]        = __float2bfloat16(a0);
    Mbb[(size_t)(64 + c)*64 + hh] = __float2bfloat16(a1);
    if (hh == 0) {
      float s0 = 0.f, s1 = 0.f;
      for (int j = 0; j < 64; ++j) {
        s0 += b2[j] * w01[j*64 + c];
        s1 += b2[j] * w11[j*64 + c];
      }
      bias0[c] = s0;
      bias1[c] = s1;
    }
  } else if (b < 1462) {              // ---- embed (320000 exact): fp32 + bf16 copies
    int i = (b-212)*256 + tid;
    int n = i >> 6, c = i & 63;
    float v = emb[an[n]*64 + c];
    node0[i] = v;
    node0b[i] = __float2bfloat16(v);
  } else if (b < 2358) {              // ---- W0rtb[col*64+u] bf16, col = h*56+vp (229376 exact)
    int idx = (b-1462)*256 + tid;
    int col = idx >> 6, u = idx & 63;
    int hh = col / 56, vp = col - hh*56;
    int boff, m3, v;
    if (vp < 32)      { boff = 0;    m3 = 32; v = vp; }
    else if (vp < 48) { boff = 2048; m3 = 16; v = vp - 32; }
    else              { boff = 3072; m3 = 8;  v = vp - 48; }
    W0rtb[idx] = __float2bfloat16(w0[hh*3584 + boff + u*m3 + v]);
  } else {                            // ---- w2t transpose + per-path [v][u] permute
    int idx = (b-2358)*256 + tid;     // 221184 exact
    int nn = idx >> 6, k = idx & 63;
    int p, loc;
    if (nn < 1024)      { p=0;  loc=nn;      }
    else if (nn < 1536) { p=1;  loc=nn-1024; }
    else if (nn < 1792) { p=2;  loc=nn-1536; }
    else if (nn < 2048) { p=3;  loc=nn-1792; }
    else if (nn < 2560) { p=4;  loc=nn-2048; }
    else if (nn < 2688) { p=5;  loc=nn-2560; }
    else if (nn < 2944) { p=6;  loc=nn-2688; }
    else if (nn < 3008) { p=7;  loc=nn-2944; }
    else if (nn < 3136) { p=8;  loc=nn-3008; }
    else if (nn < 3392) { p=9;  loc=nn-3136; }
    else                { p=10; loc=nn-3392; }
    const int M1s[11] = {32,32,32,16,16,16,16,8,8,8,8};
    const int M3s[11] = {32,16,8,16,32,8,16,8,16,32,8};
    int m1 = M1s[p], m3 = M3s[p];
    int v = loc / m1, u = loc - v*m1;
    int src = (nn - loc) + u*m3 + v;
    W2t[idx] = __float2bfloat16(w1w2[(size_t)k*3456 + src]);
  }
}

// ================= k_mid: rad (h-VALU + MFMA q-GEMM) | scan x2 =================
__global__ void __launch_bounds__(256) k_mid(
    const float* __restrict__ bc,
    const float* __restrict__ w1, const float* __restrict__ b1,
    const bf16* __restrict__ Mbb,
    const float* __restrict__ bias0, const float* __restrict__ bias1,
    float* __restrict__ q0, bf16* __restrict__ q1b,
    const int* __restrict__ hist, int* __restrict__ start,
    const int* __restrict__ hist2, int* __restrict__ start2) {
  __shared__ float smem[1024];
  __shared__ __align__(16) short sHb[2048];
  const int tid = threadIdx.x;
  const int b = blockIdx.x;
  if (b < 1563) {
    float* sW1 = smem;
    float* sB  = smem + 512;
    float* sb0 = smem + 576;
    float* sb1 = smem + 640;
    float* sBC = smem + 704;
    const int j = tid >> 6, m = tid & 63;
    for (int i = tid; i < 512; i += 256) sW1[i] = w1[i];
    if (tid < 64) { sB[tid] = b1[tid]; sb0[tid] = bias0[tid]; sb1[tid] = bias1[tid]; }
    {
      int e = b*32 + (tid >> 3);
      int k = tid & 7;
      int eL = e < E_EDGES ? e : E_EDGES-1;
      sBC[tid] = bc[(size_t)eL*8 + k];
    }
    __syncthreads();
    #pragma unroll
    for (int g = 0; g < 8; ++g) {
      int el = g*4 + j;
      float t = sB[m];
      #pragma unroll
      for (int k = 0; k < 8; ++k) t += sBC[el*8+k]*sW1[k*64+m];
      bf16 hv = __float2bfloat16(siluf(t));
      sHb[el*64 + m] = *(short*)&hv;
    }
    __syncthreads();
    const int w = tid >> 6, lane = tid & 63;
    const int row16 = lane & 15, quad = lane >> 4;
    const int mtile = w & 1, cg = w >> 1;
    const short* ap = sHb + (mtile*16 + row16)*64 + quad*8;
    short8 a0 = *(const short8*)ap;
    short8 a1 = *(const short8*)(ap + 32);
    f32x4 acc[4] = {};
    #pragma unroll
    for (int ni = 0; ni < 4; ++ni) {
      const short* bp = (const short*)Mbb + (size_t)(cg*64 + ni*16 + row16)*64 + quad*8;
      short8 b0 = *(const short8*)bp;
      short8 b1v = *(const short8*)(bp + 32);
      acc[ni] = __builtin_amdgcn_mfma_f32_16x16x32_bf16(a0, b0, acc[ni], 0,0,0);
      acc[ni] = __builtin_amdgcn_mfma_f32_16x16x32_bf16(a1, b1v, acc[ni], 0,0,0);
    }
    const float* bias = cg ? sb1 : sb0;
    #pragma unroll
    for (int ni = 0; ni < 4; ++ni) {
      int c = ni*16 + row16;
      float bv = bias[c];
      #pragma unroll
      for (int r = 0; r < 4; ++r) {
        int e = b*32 + mtile*16 + quad*4 + r;
        if (e < E_EDGES) {
          float val = siluf(acc[ni][r] + bv);
          if (cg == 0) q0[(size_t)e*64 + c] = val;
          else         q1b[(size_t)e*64 + c] = __float2bfloat16(val);
        }
      }
    }
  } else {
    const int* h = (b == 1563) ? hist : hist2;
    int* st      = (b == 1563) ? start : start2;
    int* sp = (int*)smem;
    int base = tid*20;
    int localsum = 0;
    for (int i = 0; i < 20; ++i) { int jj = base+i; localsum += (jj < NN) ? h[jj] : 0; }
    sp[tid] = localsum;
    __syncthreads();
    if (tid == 0) {
      int acc = 0;
      for (int i = 0; i < 256; ++i) { int t = sp[i]; sp[i] = acc; acc += t; }
    }
    __syncthreads();
    int run = sp[tid];
    for (int i = 0; i < 20; ++i) {
      int jj = base+i;
      if (jj < NN) { st[jj] = run; run += h[jj]; }
    }
    if (tid == 255) st[NN] = run;
  }
}

// ================= generic MFMA GEMM: out[r, :] = A[r, :64] @ B([col][64k]) =================
__global__ void __launch_bounds__(256) k_bgemm(
    const bf16* __restrict__ A, const bf16* __restrict__ B,
    bf16* __restrict__ out, int stride, int ntiles, int e0, int nE) {
  __shared__ short lds[4][32*64];
  const int tid = threadIdx.x;
  const int wid = tid >> 6, lane = tid & 63;
  const int nt = blockIdx.x*4 + wid;
  const int r0 = blockIdx.y*32;
  const int row16 = lane & 15, quad = lane >> 4;

  short8 a[2][2];
  #pragma unroll
  for (int mi = 0; mi < 2; ++mi) {
    int r = r0 + mi*16 + row16;
    int rg = e0 + ((r < nE) ? r : 0);
    const short* ap = (const short*)A + (size_t)rg*64 + quad*8;
    a[mi][0] = *(const short8*)(ap);
    a[mi][1] = *(const short8*)(ap + 32);
  }
  if (nt < ntiles) {
    f32x4 acc[4][2] = {};
    #pragma unroll
    for (int ni = 0; ni < 4; ++ni) {
      int col = nt*64 + ni*16 + row16;
      const short* bp = (const short*)B + (size_t)col*64 + quad*8;
      short8 b0 = *(const short8*)(bp);
      short8 b1 = *(const short8*)(bp + 32);
      #pragma unroll
      for (int mi = 0; mi < 2; ++mi) {
        acc[ni][mi] = __builtin_amdgcn_mfma_f32_16x16x32_bf16(a[mi][0], b0, acc[ni][mi], 0,0,0);
        acc[ni][mi] = __builtin_amdgcn_mfma_f32_16x16x32_bf16(a[mi][1], b1, acc[ni][mi], 0,0,0);
      }
    }
    #pragma unroll
    for (int ni = 0; ni < 4; ++ni)
      #pragma unroll
      for (int mi = 0; mi < 2; ++mi)
        #pragma unroll
        for (int rr = 0; rr < 4; ++rr) {
          bf16 hv = __float2bfloat16(acc[ni][mi][rr]);
          lds[wid][(mi*16 + quad*4 + rr)*64 + ni*16 + row16] = *(short*)&hv;
        }
  }
  __syncthreads();
  if (nt < ntiles) {
    #pragma unroll
    for (int it = 0; it < 4; ++it) {
      int unit = it*64 + lane;
      int rrow = unit >> 3;
      int cu = (unit & 7) * 8;
      int r = r0 + rrow;
      if (r < nE)
        *(uint4*)((short*)out + (size_t)r*stride + nt*64 + cu) =
            *(const uint4*)&lds[wid][rrow*64 + cu];
    }
  }
}

// ================= CSR scatter (src + dst) =================
__global__ void k_scat(const int* __restrict__ ei,
                       const int* __restrict__ start, int* __restrict__ cursor,
                       int* __restrict__ perm,
                       const int* __restrict__ start2, int* __restrict__ cursor2,
                       int* __restrict__ perm2) {
  int e = blockIdx.x*256 + threadIdx.x;
  if (e >= E_EDGES) return;
  int src = ei[e];
  perm[start[src] + atomicAdd(&cursor[src], 1)] = e;
  int dst = ei[E_EDGES + e];
  perm2[start2[dst] + atomicAdd(&cursor2[dst], 1)] = e;
}

// ================= layer-0 z: per-src-node; G0 row in LDS; z -> zbuf (no atomics) =================
__global__ void __launch_bounds__(256) k_msg0z(
    const float* __restrict__ q0, const bf16* __restrict__ G0,
    const int* __restrict__ start, const int* __restrict__ perm,
    float* __restrict__ zbuf) {
  __shared__ uint4 g4[448];
  __shared__ float sq[4][64];
  const int n = blockIdx.x;
  const int tid = threadIdx.x;
  const int wv = tid >> 6, lane = tid & 63;
  const uint4* gr = (const uint4*)(G0 + (size_t)n*3584);
  for (int i = tid; i < 448; i += 256) g4[i] = gr[i];
  const int s0 = start[n], s1 = start[n+1];
  __syncthreads();
  const short* gs = (const short*)g4;
  for (int base = s0; base < s1; base += 4) {
    int idx = base + wv;
    if (idx < s1) {
      int e = perm[idx];
      sq[wv][lane] = q0[(size_t)e*64 + lane];
      float z = 0.f;
      if (lane < 56) {
        #pragma unroll
        for (int h = 0; h < 64; ++h)
          z += sq[wv][h]*us2f((unsigned short)gs[h*56 + lane]);
        zbuf[(size_t)e*56 + lane] = z;
      }
    }
  }
}

// ================= layer-0 aggregate (dst-CSR) + self-connection -> node1 =================
__global__ void k_agg0(const float* __restrict__ zbuf, const float* __restrict__ shb,
                       const int* __restrict__ start2, const int* __restrict__ perm2,
                       const float* __restrict__ node0, const float* __restrict__ sc00,
                       float* __restrict__ node1) {
  __shared__ float n0[64];
  int n = blockIdx.x, tid = threadIdx.x;
  if (tid < 64) n0[tid] = node0[(size_t)n*64 + tid];
  __syncthreads();
  if (tid >= 120) return;
  int c = tid, zi, shi;
  if (c < 32)      { zi = c; shi = -1; }
  else if (c < 80) { int j = c-32, v = j/3, k = j - v*3; zi = 32 + v; shi = 1 + k; }
  else             { int j = c-80, v = j/5, k = j - v*5; zi = 48 + v; shi = 4 + k; }
  float acc = 0.f;
  const int s0 = start2[n], s1 = start2[n+1];
  for (int idx = s0; idx < s1; ++idx) {
    int e = perm2[idx];
    float z = zbuf[(size_t)e*56 + zi];
    acc += (shi < 0) ? z : z*shb[(size_t)e*12 + shi];
  }
  acc *= 0.125f * 0.3162277660168379f;
  if (c < 32) {
    float s = 0.f;
    for (int u = 0; u < 64; ++u) s += n0[u]*sc00[u*32 + c];
    acc += s * 0.125f;
    acc = siluf(acc);
  }
  node1[(size_t)n*120 + c] = acc;
}

// ================= layer-1 consume: one wave/edge; msg -> msg1 (no atomics) =================
__global__ void __launch_bounds__(256) k_tp4(
    const bf16* __restrict__ wch, const float* __restrict__ node1,
    const float* __restrict__ shb, const int* __restrict__ ei,
    int e0, int nE, float* __restrict__ msg1) {
  __shared__ float tl[4][592];
  __shared__ float xl[4][120];
  __shared__ float shl[4][12];
  const int tid = threadIdx.x;
  const int wv = tid >> 6, lane = tid & 63;
  int elr = blockIdx.x*4 + wv;
  const bool live = elr < nE;
  const int el = live ? elr : nE-1;
  const int eg = e0 + el;
  const int src = ei[eg];

  for (int i = lane; i < 120; i += 64) xl[wv][i] = node1[(size_t)src*120 + i];
  if (lane < 12) shl[wv][lane] = shb[(size_t)eg*12 + lane];
  __syncthreads();

  {
    const float* x  = xl[wv];
    const float* sh = shl[wv];
    const float A = 0.3162277660168379f, Bc = 0.1825741858350554f, B2 = 0.3651483716701107f;
    const int I_[11] = {0,2,0,1,1,2, 0,1,2, 0,2};
    const int J_[11] = {2,0,1,0,2,1, 0,1,2, 0,2};
    const int K_[11] = {0,0,1,1,3,3, 2,2,2, 4,4};
    const float V_[11] = {A,A,A,A,A,A, -Bc,B2,-Bc, -A,A};
    for (int idx = lane; idx < 592; idx += 64) {
      float t = 0.0f;
      if (idx < 32)       { t = x[idx] * 0.1336306209562122f; }
      else if (idx < 128) { int j = idx-32,  u=j/3, k=j-u*3; t = x[u]*sh[1+k] * 0.1178511301977579f; }
      else if (idx < 288) { int j = idx-128, u=j/5, k=j-u*5; t = x[u]*sh[4+k] * 0.125f; }
      else if (idx < 336) { int j = idx-288, u=j/3, k=j-u*3; t = x[32+u*3+k] * 0.1178511301977579f; }
      else if (idx < 352) { int u = idx-336;
        t = (x[32+u*3]*sh[1] + x[32+u*3+1]*sh[2] + x[32+u*3+2]*sh[3]) * 0.0771516749810460f; }
      else if (idx < 432) { int j = idx-352, u=j/5, k=j-u*5;
        float s = 0.f;
        #pragma unroll
        for (int q = 0; q < 11; ++q) if (K_[q] == k)
          s += V_[q]*x[32+u*3+I_[q]]*sh[1+J_[q]];
        t = s * 0.2795084971874737f; }
      else if (idx < 480) { int j = idx-432, u=j/3, k=j-u*3;
        float s = 0.f;
        #pragma unroll
        for (int q = 0; q < 11; ++q) if (J_[q] == k)
          s += V_[q]*x[32+u*3+I_[q]]*sh[4+K_[q]];
        t = s * 0.2041241452319315f; }
      else if (idx < 520) { int j = idx-480, u=j/5, k=j-u*5; t = x[80+u*5+k] * 0.125f; }
      else if (idx < 544) { int j = idx-520, u=j/3, k=j-u*3;
        float s = 0.f;
        #pragma unroll
        for (int q = 0; q < 11; ++q) if (J_[q] == k)
          s += V_[q]*x[80+u*5+K_[q]]*sh[1+I_[q]];
        t = s * 0.2041241452319315f; }
      else if (idx < 552) { int u = idx-544;
        float s = 0.f;
        #pragma unroll
        for (int q = 0; q < 5; ++q) s += x[80+u*5+q]*sh[4+q];
        t = s * 0.0597614304667197f; }
      else { int j = idx-552, u=j/5, k=j-u*5;
        const float P = 0.2390457218668787f, Q = 0.2070196678027063f, R = 0.1195228609334394f;
        const int I2_[25] = {0,0,2, 0,0,1,1,3,3, 1,1,2, 1,1,4, 2, 2,3,3, 2,4,4, 3,3,4};
        const int J2_[25] = {0,2,0, 1,3,0,3,0,1, 1,2,1, 1,4,1, 2, 3,2,3, 4,2,4, 3,4,3};
        const int K2_[25] = {2,0,0, 3,1,3,0,1,0, 2,1,1, 4,1,1, 2, 3,3,2, 4,4,2, 4,3,3};
        const float V2_[25] = {P,P,P, -Q,-Q,-Q,-Q,-Q,-Q, -R,-R,-R, Q,Q,Q, -P,
                               -R,-R,-R, P,P,P, -Q,-Q,-Q};
        float s = 0.f;
        #pragma unroll
        for (int q = 0; q < 25; ++q) if (K2_[q] == k)
          s += V2_[q]*x[80+u*5+I2_[q]]*sh[4+J2_[q]];
        t = s * 0.2795084971874737f; }
      tl[wv][idx] = t;
    }
  }
  __syncthreads();

  const short* wrow = (const short*)wch + (size_t)el*3456;
  const float* t = tl[wv];
  float r0 = 0.f, r1 = 0.f, r2 = 0.f;
  #define PATHC(OFF, M1C, NKC, TOFFC, REG)                                  \
    { int v = lane / (NKC), k = lane - v*(NKC);                             \
      const short* wp = wrow + (OFF) + v*(M1C);                             \
      _Pragma("unroll")                                                     \
      for (int ub = 0; ub < (M1C)/8; ++ub) {                                \
        short8 w8 = *(const short8*)(wp + ub*8);                            \
        _Pragma("unroll")                                                   \
        for (int r = 0; r < 8; ++r)                                         \
          REG += us2f((unsigned short)w8[r]) * t[(TOFFC)+(ub*8+r)*(NKC)+k]; \
      } }
  if (lane < 32) {
    PATHC(0,    32, 1, 0,   r0)
    PATHC(2048, 16, 1, 336, r0)
    PATHC(3136,  8, 1, 544, r0)
  }
  if (lane < 48) {
    PATHC(1024, 32, 3, 32,  r1)
    PATHC(1792, 16, 3, 288, r1)
    PATHC(2688, 16, 3, 432, r1)
    PATHC(3008,  8, 3, 520, r1)
  }
  if (lane < 40) {
    PATHC(1536, 32, 5, 128, r2)
    PATHC(2560, 16, 5, 352, r2)
    PATHC(2944,  8, 5, 480, r2)
    PATHC(3392,  8, 5, 552, r2)
  }
  #undef PATHC

  if (live) {
    const float s = 0.3162277660168379f;
    float* mp = msg1 + (size_t)eg*120;
    if (lane < 32) mp[lane] = r0*s;
    if (lane < 48) mp[32 + lane] = r1*s;
    if (lane < 40) mp[80 + lane] = r2*s;
  }
}

// ================= output: dst-CSR msg1 aggregation + self-connection =================
__global__ void k_out(const float* __restrict__ msg1,
                      const int* __restrict__ start2, const int* __restrict__ perm2,
                      const float* __restrict__ node1,
                      const float* __restrict__ sc0e, const float* __restrict__ sc1o,
                      const float* __restrict__ sc2e, float* __restrict__ out) {
  __shared__ float x[120];
  int n = blockIdx.x, tid = threadIdx.x;
  if (tid < 120) x[tid] = node1[(size_t)n*120 + tid];
  __syncthreads();
  if (tid >= 120) return;
  float v = 0.f;
  const int s0 = start2[n], s1 = start2[n+1];
  for (int idx = s0; idx < s1; ++idx)
    v += msg1[(size_t)perm2[idx]*120 + tid];
  if (tid < 32) {
    float s = 0.f;
    for (int u = 0; u < 32; ++u) s += x[u]*sc0e[u*32 + tid];
    v += s * 0.1767766952966369f;
  } else if (tid < 80) {
    int jj = tid - 32, vv = jj/3, k = jj - vv*3;
    float s = 0.f;
    for (int u = 0; u < 16; ++u) s += x[32 + u*3 + k]*sc1o[u*16 + vv];
    v += s * 0.25f;
  } else {
    int jj = tid - 80, vv = jj/5, k = jj - vv*5;
    float s = 0.f;
    for (int u = 0; u < 8; ++u) s += x[80 + u*5 + k]*sc2e[u*8 + vv];
    v += s * 0.3535533905932738f;
  }
  out[(size_t)n*120 + tid] = v;
}

// ---------------- launch ----------------
extern "C" void kernel_launch(void* const* d_in, const int* in_sizes, int n_in,
                              void* d_out, int out_size, void* d_ws, size_t ws_size,
                              hipStream_t stream) {
  const float* embed   = (const float*)d_in[1];
  const float* rad_w1  = (const float*)d_in[2];
  const float* rad_b1  = (const float*)d_in[3];
  const float* rad_w2  = (const float*)d_in[4];
  const float* rad_b2  = (const float*)d_in[5];
  const float* wnn0_w1 = (const float*)d_in[6];
  const float* wnn0_w2 = (const float*)d_in[7];
  const float* wnn1_w1 = (const float*)d_in[8];
  const float* wnn1_w2 = (const float*)d_in[9];
  const float* sc0_0e  = (const float*)d_in[10];
  const float* sc1_0e  = (const float*)d_in[11];
  const float* sc1_1o  = (const float*)d_in[12];
  const float* sc1_2e  = (const float*)d_in[13];
  const float* edge_vec = (const float*)d_in[14];
  const float* edge_len = (const float*)d_in[15];
  const int*  anum    = (const int*)d_in[16];
  const int*  ei      = (const int*)d_in[17];

  float* ws = (float*)d_ws;
  float* shbuf = ws;                        // 600000
  float* bc    = ws + 600000;               // 400000
  bf16*  q1b   = (bf16*)(ws + 1000000);     // 1.6M f-slots
  float* node0 = ws + 2600000;              // 320000
  bf16*  node0b= (bf16*)(ws + 2920000);     // 160000 f-slots
  bf16*  W0rtb = (bf16*)(ws + 3080000);     // 114688 f-slots
  bf16*  W2t   = (bf16*)(ws + 3194688);     // 110592 f-slots
  bf16*  Mbb   = (bf16*)(ws + 3305280);     // 4096 f-slots
  float* bias0 = ws + 3309376;              // 64
  float* bias1 = ws + 3309440;              // 64
  int*   hist   = (int*)(ws + 3309504);     // 5000 (memset covers hist..cursor2)
  int*   cursor = (int*)(ws + 3314504);     // 5000
  int*   hist2  = (int*)(ws + 3319504);     // 5000
  int*   cursor2= (int*)(ws + 3324504);     // 5000
  int*   start  = (int*)(ws + 3329504);     // 5008
  int*   start2 = (int*)(ws + 3334512);     // 5008
  int*   perm   = (int*)(ws + 3339520);     // 50000
  int*   perm2  = (int*)(ws + 3389520);     // 50000
  float* node1 = ws + 3439520;              // 600000
  float* zbuf  = ws + 4039520;              // 2800000 (50000 x 56)
  float* msg1  = ws + 6839520;              // 6000000 (50000 x 120)
  float* q0    = ws + 12839520;             // 3200000
  bf16*  G0    = (bf16*)(ws + 16039520);    // 8.96M f-slots -> base end 24999520 (100 MB)

  long long CH; bf16* wbuf;
  const size_t base_end = 24999520ull;
  if (ws_size >= (base_end + 21600000ull)*4) { CH = 12500; wbuf = (bf16*)(ws + base_end); }
  else                                       { CH = 6250;  wbuf = (bf16*)(ws + 12839520); } // alias q0+G0

  hipMemsetAsync(hist, 0, 20000*sizeof(int), stream);   // hist, cursor, hist2, cursor2

  k_setup<<<3222, 256, 0, stream>>>(edge_vec, edge_len, shbuf, bc,
                                    rad_w2, rad_b2, wnn0_w1, wnn1_w1, Mbb, bias0, bias1,
                                    embed, anum, node0, node0b,
                                    wnn0_w2, W0rtb, wnn1_w2, W2t, ei, hist, hist2);
  k_mid<<<1565, 256, 0, stream>>>(bc, rad_w1, rad_b1, Mbb, bias0, bias1,
                                  q0, q1b, hist, start, hist2, start2);
  k_bgemm<<<dim3(14, (NN+31)/32), 256, 0, stream>>>(node0b, W0rtb, G0, 3584, 56, 0, NN);
  k_scat<<<196, 256, 0, stream>>>(ei, start, cursor, perm, start2, cursor2, perm2);
  k_msg0z<<<NN, 256, 0, stream>>>(q0, G0, start, perm, zbuf);
  k_agg0<<<NN, 128, 0, stream>>>(zbuf, shbuf, start2, perm2, node0, sc0_0e, node1);

  for (long long e0 = 0; e0 < E_EDGES; e0 += CH) {
    k_bgemm<<<dim3(14, (unsigned)((CH+31)/32), 1), 256, 0, stream>>>(q1b, W2t, wbuf, 3456, 54, (int)e0, (int)CH);
    k_tp4<<<(unsigned)((CH+3)/4), 256, 0, stream>>>(wbuf, node1, shbuf, ei, (int)e0, (int)CH, msg1);
  }
  k_out<<<NN, 128, 0, stream>>>(msg1, start2, perm2, node1, sc1_0e, sc1_1o, sc1_2e, (float*)d_out);
}

// Round 15
// 465.712 us; speedup vs baseline: 1.2522x; 1.0762x over previous
//
#include <hip/hip_runtime.h>
#include <hip/hip_bf16.h>
#include <math.h>

#define E_EDGES 50000
#define NN 5000

typedef __hip_bfloat16 bf16;
typedef __attribute__((ext_vector_type(8))) short short8;
typedef __attribute__((ext_vector_type(4))) float f32x4;

__device__ __forceinline__ float b2f(bf16 v) { return __bfloat162float(v); }
__device__ __forceinline__ float siluf(float x) { return x / (1.0f + __expf(-x)); }
__device__ __forceinline__ float us2f(unsigned short u) {
  union { unsigned int i; float f; } c; c.i = ((unsigned int)u) << 16; return c.f;
}

// ================= merged setup: prep(+hists) | fuse->Mbb | embed | w0rtb | w2t =================
__global__ void __launch_bounds__(256) k_setup(
    const float* __restrict__ evec, const float* __restrict__ elen,
    float* __restrict__ shb, float* __restrict__ bc,
    const float* __restrict__ w2, const float* __restrict__ b2,
    const float* __restrict__ w01, const float* __restrict__ w11,
    bf16* __restrict__ Mbb,
    float* __restrict__ bias0, float* __restrict__ bias1,
    const float* __restrict__ emb, const int* __restrict__ an,
    float* __restrict__ node0, bf16* __restrict__ node0b,
    const float* __restrict__ w0, bf16* __restrict__ W0rtb,
    const float* __restrict__ w1w2, bf16* __restrict__ W2t,
    const int* __restrict__ ei, int* __restrict__ hist, int* __restrict__ hist2) {
  const int b = blockIdx.x, tid = threadIdx.x;
  if (b < 196) {                      // ---- prep (sh + basis*cutoff) + src/dst histograms
    int e = b*256 + tid;
    if (e >= E_EDGES) return;
    atomicAdd(&hist[ei[e]], 1);
    atomicAdd(&hist2[ei[E_EDGES + e]], 1);
    float x = evec[3*e+0], y = evec[3*e+1], z = evec[3*e+2];
    float r = elen[e];
    float inv = 1.0f / (r + 1e-8f);
    float ux = x*inv, uy = y*inv, uz = z*inv;
    const float s3 = 1.7320508075688772f, s5 = 2.2360679774997896f, s15 = 3.8729833462074170f;
    float* sh = shb + (size_t)e*12;
    sh[0] = 1.0f;
    sh[1] = s3*uy; sh[2] = s3*uz; sh[3] = s3*ux;
    sh[4] = s15*ux*uy; sh[5] = s15*uy*uz; sh[6] = 0.5f*s5*(3.0f*uz*uz - 1.0f);
    sh[7] = s15*ux*uz; sh[8] = 0.5f*s15*(ux*ux - uy*uy);
    sh[9] = 0.f; sh[10] = 0.f; sh[11] = 0.f;
    float rr = fmaxf(r, 1e-8f);
    const float pi = 3.14159265358979f;
    float xr = r * 0.2f;
    float cut = (xr < 1.0f) ? 0.5f*(1.0f + cosf(pi*xr)) : 0.0f;
    float fb = pi * 0.2f;
    for (int k = 1; k <= 8; ++k)
      bc[(size_t)e*8 + (k-1)] = sinf(fb*(float)k*r)/rr * cut;
  } else if (b < 212) {               // ---- fuse rad_w2 into wnn*_w1 -> Mbb (B-layout bf16)
    int i = (b-196)*256 + tid;        // 4096
    int hh = i >> 6, c = i & 63;
    float a0 = 0.f, a1 = 0.f;
    for (int j = 0; j < 64; ++j) {
      float wv = w2[hh*64 + j];
      a0 += wv * w01[j*64 + c];
      a1 += wv * w11[j*64 + c];
    }
    Mbb[(size_t)c*64 + hh]        = __float2bfloat16(a0);
    Mbb[(size_t)(64 + c)*64 + hh] = __float2bfloat16(a1);
    if (hh == 0) {
      float s0 = 0.f, s1 = 0.f;
      for (int j = 0; j < 64; ++j) {
        s0 += b2[j] * w01[j*64 + c];
        s1 += b2[j] * w11[j*64 + c];
      }
      bias0[c] = s0;
      bias1[c] = s1;
    }
  } else if (b < 1462) {              // ---- embed (320000 exact): fp32 + bf16 copies
    int i = (b-212)*256 + tid;
    int n = i >> 6, c = i & 63;
    float v = emb[an[n]*64 + c];
    node0[i] = v;
    node0b[i] = __float2bfloat16(v);
  } else if (b < 2358) {              // ---- W0rtb[col*64+u] bf16, col = h*56+vp (229376 exact)
    int idx = (b-1462)*256 + tid;
    int col = idx >> 6, u = idx & 63;
    int hh = col / 56, vp = col - hh*56;
    int boff, m3, v;
    if (vp < 32)      { boff = 0;    m3 = 32; v = vp; }
    else if (vp < 48) { boff = 2048; m3 = 16; v = vp - 32; }
    else              { boff = 3072; m3 = 8;  v = vp - 48; }
    W0rtb[idx] = __float2bfloat16(w0[hh*3584 + boff + u*m3 + v]);
  } else {                            // ---- w2t transpose + per-path [v][u] permute
    int idx = (b-2358)*256 + tid;     // 221184 exact
    int nn = idx >> 6, k = idx & 63;
    int p, loc;
    if (nn < 1024)      { p=0;  loc=nn;      }
    else if (nn < 1536) { p=1;  loc=nn-1024; }
    else if (nn < 1792) { p=2;  loc=nn-1536; }
    else if (nn < 2048) { p=3;  loc=nn-1792; }
    else if (nn < 2560) { p=4;  loc=nn-2048; }
    else if (nn < 2688) { p=5;  loc=nn-2560; }
    else if (nn < 2944) { p=6;  loc=nn-2688; }
    else if (nn < 3008) { p=7;  loc=nn-2944; }
    else if (nn < 3136) { p=8;  loc=nn-3008; }
    else if (nn < 3392) { p=9;  loc=nn-3136; }
    else                { p=10; loc=nn-3392; }
    const int M1s[11] = {32,32,32,16,16,16,16,8,8,8,8};
    const int M3s[11] = {32,16,8,16,32,8,16,8,16,32,8};
    int m1 = M1s[p], m3 = M3s[p];
    int v = loc / m1, u = loc - v*m1;
    int src = (nn - loc) + u*m3 + v;
    W2t[idx] = __float2bfloat16(w1w2[(size_t)k*3456 + src]);
  }
}

// ================= k_mid: rad (h-VALU + MFMA q-GEMM) | scan x2 =================
__global__ void __launch_bounds__(256) k_mid(
    const float* __restrict__ bc,
    const float* __restrict__ w1, const float* __restrict__ b1,
    const bf16* __restrict__ Mbb,
    const float* __restrict__ bias0, const float* __restrict__ bias1,
    float* __restrict__ q0, bf16* __restrict__ q1b,
    const int* __restrict__ hist, int* __restrict__ start,
    const int* __restrict__ hist2, int* __restrict__ start2) {
  __shared__ float smem[1024];
  __shared__ __align__(16) short sHb[2048];
  const int tid = threadIdx.x;
  const int b = blockIdx.x;
  if (b < 1563) {
    float* sW1 = smem;
    float* sB  = smem + 512;
    float* sb0 = smem + 576;
    float* sb1 = smem + 640;
    float* sBC = smem + 704;
    const int j = tid >> 6, m = tid & 63;
    for (int i = tid; i < 512; i += 256) sW1[i] = w1[i];
    if (tid < 64) { sB[tid] = b1[tid]; sb0[tid] = bias0[tid]; sb1[tid] = bias1[tid]; }
    {
      int e = b*32 + (tid >> 3);
      int k = tid & 7;
      int eL = e < E_EDGES ? e : E_EDGES-1;
      sBC[tid] = bc[(size_t)eL*8 + k];
    }
    __syncthreads();
    #pragma unroll
    for (int g = 0; g < 8; ++g) {
      int el = g*4 + j;
      float t = sB[m];
      #pragma unroll
      for (int k = 0; k < 8; ++k) t += sBC[el*8+k]*sW1[k*64+m];
      bf16 hv = __float2bfloat16(siluf(t));
      sHb[el*64 + m] = *(short*)&hv;
    }
    __syncthreads();
    const int w = tid >> 6, lane = tid & 63;
    const int row16 = lane & 15, quad = lane >> 4;
    const int mtile = w & 1, cg = w >> 1;
    const short* ap = sHb + (mtile*16 + row16)*64 + quad*8;
    short8 a0 = *(const short8*)ap;
    short8 a1 = *(const short8*)(ap + 32);
    f32x4 acc[4] = {};
    #pragma unroll
    for (int ni = 0; ni < 4; ++ni) {
      const short* bp = (const short*)Mbb + (size_t)(cg*64 + ni*16 + row16)*64 + quad*8;
      short8 b0 = *(const short8*)bp;
      short8 b1v = *(const short8*)(bp + 32);
      acc[ni] = __builtin_amdgcn_mfma_f32_16x16x32_bf16(a0, b0, acc[ni], 0,0,0);
      acc[ni] = __builtin_amdgcn_mfma_f32_16x16x32_bf16(a1, b1v, acc[ni], 0,0,0);
    }
    const float* bias = cg ? sb1 : sb0;
    #pragma unroll
    for (int ni = 0; ni < 4; ++ni) {
      int c = ni*16 + row16;
      float bv = bias[c];
      #pragma unroll
      for (int r = 0; r < 4; ++r) {
        int e = b*32 + mtile*16 + quad*4 + r;
        if (e < E_EDGES) {
          float val = siluf(acc[ni][r] + bv);
          if (cg == 0) q0[(size_t)e*64 + c] = val;
          else         q1b[(size_t)e*64 + c] = __float2bfloat16(val);
        }
      }
    }
  } else {
    const int* h = (b == 1563) ? hist : hist2;
    int* st      = (b == 1563) ? start : start2;
    int* sp = (int*)smem;
    int base = tid*20;
    int localsum = 0;
    for (int i = 0; i < 20; ++i) { int jj = base+i; localsum += (jj < NN) ? h[jj] : 0; }
    sp[tid] = localsum;
    __syncthreads();
    if (tid == 0) {
      int acc = 0;
      for (int i = 0; i < 256; ++i) { int t = sp[i]; sp[i] = acc; acc += t; }
    }
    __syncthreads();
    int run = sp[tid];
    for (int i = 0; i < 20; ++i) {
      int jj = base+i;
      if (jj < NN) { st[jj] = run; run += h[jj]; }
    }
    if (tid == 255) st[NN] = run;
  }
}

// ================= k_pre0: scat (src+dst CSR) | G0 MFMA GEMM (flattened) =================
__global__ void __launch_bounds__(256) k_pre0(
    const int* __restrict__ ei,
    const int* __restrict__ start, int* __restrict__ cursor, int* __restrict__ perm,
    const int* __restrict__ start2, int* __restrict__ cursor2, int* __restrict__ perm2,
    const bf16* __restrict__ A, const bf16* __restrict__ B, bf16* __restrict__ out) {
  __shared__ short lds[4][32*64];
  const int b = blockIdx.x, tid = threadIdx.x;
  if (b < 196) {
    int e = b*256 + tid;
    if (e >= E_EDGES) return;
    int src = ei[e];
    perm[start[src] + atomicAdd(&cursor[src], 1)] = e;
    int dst = ei[E_EDGES + e];
    perm2[start2[dst] + atomicAdd(&cursor2[dst], 1)] = e;
  } else {
    const int bb = b - 196;           // 14 x 157 blocks
    const int wid = tid >> 6, lane = tid & 63;
    const int nt = (bb % 14)*4 + wid;
    const int r0 = (bb / 14)*32;
    const int row16 = lane & 15, quad = lane >> 4;
    short8 a[2][2];
    #pragma unroll
    for (int mi = 0; mi < 2; ++mi) {
      int r = r0 + mi*16 + row16;
      int rg = (r < NN) ? r : 0;
      const short* ap = (const short*)A + (size_t)rg*64 + quad*8;
      a[mi][0] = *(const short8*)(ap);
      a[mi][1] = *(const short8*)(ap + 32);
    }
    if (nt < 56) {
      f32x4 acc[4][2] = {};
      #pragma unroll
      for (int ni = 0; ni < 4; ++ni) {
        int col = nt*64 + ni*16 + row16;
        const short* bp = (const short*)B + (size_t)col*64 + quad*8;
        short8 b0 = *(const short8*)(bp);
        short8 b1 = *(const short8*)(bp + 32);
        #pragma unroll
        for (int mi = 0; mi < 2; ++mi) {
          acc[ni][mi] = __builtin_amdgcn_mfma_f32_16x16x32_bf16(a[mi][0], b0, acc[ni][mi], 0,0,0);
          acc[ni][mi] = __builtin_amdgcn_mfma_f32_16x16x32_bf16(a[mi][1], b1, acc[ni][mi], 0,0,0);
        }
      }
      #pragma unroll
      for (int ni = 0; ni < 4; ++ni)
        #pragma unroll
        for (int mi = 0; mi < 2; ++mi)
          #pragma unroll
          for (int rr = 0; rr < 4; ++rr) {
            bf16 hv = __float2bfloat16(acc[ni][mi][rr]);
            lds[wid][(mi*16 + quad*4 + rr)*64 + ni*16 + row16] = *(short*)&hv;
          }
    }
    __syncthreads();
    if (nt < 56) {
      #pragma unroll
      for (int it = 0; it < 4; ++it) {
        int unit = it*64 + lane;
        int rrow = unit >> 3;
        int cu = (unit & 7) * 8;
        int r = r0 + rrow;
        if (r < NN)
          *(uint4*)((short*)out + (size_t)r*3584 + nt*64 + cu) =
              *(const uint4*)&lds[wid][rrow*64 + cu];
      }
    }
  }
}

// ================= generic MFMA GEMM: out[r, :] = A[r, :64] @ B([col][64k]) =================
__global__ void __launch_bounds__(256) k_bgemm(
    const bf16* __restrict__ A, const bf16* __restrict__ B,
    bf16* __restrict__ out, int stride, int ntiles, int e0, int nE) {
  __shared__ short lds[4][32*64];
  const int tid = threadIdx.x;
  const int wid = tid >> 6, lane = tid & 63;
  const int nt = blockIdx.x*4 + wid;
  const int r0 = blockIdx.y*32;
  const int row16 = lane & 15, quad = lane >> 4;

  short8 a[2][2];
  #pragma unroll
  for (int mi = 0; mi < 2; ++mi) {
    int r = r0 + mi*16 + row16;
    int rg = e0 + ((r < nE) ? r : 0);
    const short* ap = (const short*)A + (size_t)rg*64 + quad*8;
    a[mi][0] = *(const short8*)(ap);
    a[mi][1] = *(const short8*)(ap + 32);
  }
  if (nt < ntiles) {
    f32x4 acc[4][2] = {};
    #pragma unroll
    for (int ni = 0; ni < 4; ++ni) {
      int col = nt*64 + ni*16 + row16;
      const short* bp = (const short*)B + (size_t)col*64 + quad*8;
      short8 b0 = *(const short8*)(bp);
      short8 b1 = *(const short8*)(bp + 32);
      #pragma unroll
      for (int mi = 0; mi < 2; ++mi) {
        acc[ni][mi] = __builtin_amdgcn_mfma_f32_16x16x32_bf16(a[mi][0], b0, acc[ni][mi], 0,0,0);
        acc[ni][mi] = __builtin_amdgcn_mfma_f32_16x16x32_bf16(a[mi][1], b1, acc[ni][mi], 0,0,0);
      }
    }
    #pragma unroll
    for (int ni = 0; ni < 4; ++ni)
      #pragma unroll
      for (int mi = 0; mi < 2; ++mi)
        #pragma unroll
        for (int rr = 0; rr < 4; ++rr) {
          bf16 hv = __float2bfloat16(acc[ni][mi][rr]);
          lds[wid][(mi*16 + quad*4 + rr)*64 + ni*16 + row16] = *(short*)&hv;
        }
  }
  __syncthreads();
  if (nt < ntiles) {
    #pragma unroll
    for (int it = 0; it < 4; ++it) {
      int unit = it*64 + lane;
      int rrow = unit >> 3;
      int cu = (unit & 7) * 8;
      int r = r0 + rrow;
      if (r < nE)
        *(uint4*)((short*)out + (size_t)r*stride + nt*64 + cu) =
            *(const uint4*)&lds[wid][rrow*64 + cu];
    }
  }
}

// ================= layer-0 z: per-src-node; G0 row in LDS; z -> zbuf (no atomics) =================
__global__ void __launch_bounds__(256) k_msg0z(
    const float* __restrict__ q0, const bf16* __restrict__ G0,
    const int* __restrict__ start, const int* __restrict__ perm,
    float* __restrict__ zbuf) {
  __shared__ uint4 g4[448];
  __shared__ float sq[4][64];
  const int n = blockIdx.x;
  const int tid = threadIdx.x;
  const int wv = tid >> 6, lane = tid & 63;
  const uint4* gr = (const uint4*)(G0 + (size_t)n*3584);
  for (int i = tid; i < 448; i += 256) g4[i] = gr[i];
  const int s0 = start[n], s1 = start[n+1];
  __syncthreads();
  const short* gs = (const short*)g4;
  for (int base = s0; base < s1; base += 4) {
    int idx = base + wv;
    if (idx < s1) {
      int e = perm[idx];
      sq[wv][lane] = q0[(size_t)e*64 + lane];
      float z = 0.f;
      if (lane < 56) {
        #pragma unroll
        for (int h = 0; h < 64; ++h)
          z += sq[wv][h]*us2f((unsigned short)gs[h*56 + lane]);
        zbuf[(size_t)e*56 + lane] = z;
      }
    }
  }
}

// ================= layer-0 aggregate (dst-CSR) + self-connection -> node1 =================
__global__ void k_agg0(const float* __restrict__ zbuf, const float* __restrict__ shb,
                       const int* __restrict__ start2, const int* __restrict__ perm2,
                       const float* __restrict__ node0, const float* __restrict__ sc00,
                       float* __restrict__ node1) {
  __shared__ float n0[64];
  int n = blockIdx.x, tid = threadIdx.x;
  if (tid < 64) n0[tid] = node0[(size_t)n*64 + tid];
  __syncthreads();
  if (tid >= 120) return;
  int c = tid, zi, shi;
  if (c < 32)      { zi = c; shi = -1; }
  else if (c < 80) { int j = c-32, v = j/3, k = j - v*3; zi = 32 + v; shi = 1 + k; }
  else             { int j = c-80, v = j/5, k = j - v*5; zi = 48 + v; shi = 4 + k; }
  float acc = 0.f;
  const int s0 = start2[n], s1 = start2[n+1];
  for (int idx = s0; idx < s1; ++idx) {
    int e = perm2[idx];
    float z = zbuf[(size_t)e*56 + zi];
    acc += (shi < 0) ? z : z*shb[(size_t)e*12 + shi];
  }
  acc *= 0.125f * 0.3162277660168379f;
  if (c < 32) {
    float s = 0.f;
    for (int u = 0; u < 64; ++u) s += n0[u]*sc00[u*32 + c];
    acc += s * 0.125f;
    acc = siluf(acc);
  }
  node1[(size_t)n*120 + c] = acc;
}

// ================= layer-1 consume: one wave/edge; msg -> msg1 (no atomics) =================
__global__ void __launch_bounds__(256) k_tp4(
    const bf16* __restrict__ wch, const float* __restrict__ node1,
    const float* __restrict__ shb, const int* __restrict__ ei,
    int e0, int nE, float* __restrict__ msg1) {
  __shared__ float tl[4][592];
  __shared__ float xl[4][120];
  __shared__ float shl[4][12];
  const int tid = threadIdx.x;
  const int wv = tid >> 6, lane = tid & 63;
  int elr = blockIdx.x*4 + wv;
  const bool live = elr < nE;
  const int el = live ? elr : nE-1;
  const int eg = e0 + el;
  const int src = ei[eg];

  for (int i = lane; i < 120; i += 64) xl[wv][i] = node1[(size_t)src*120 + i];
  if (lane < 12) shl[wv][lane] = shb[(size_t)eg*12 + lane];
  __syncthreads();

  {
    const float* x  = xl[wv];
    const float* sh = shl[wv];
    const float A = 0.3162277660168379f, Bc = 0.1825741858350554f, B2 = 0.3651483716701107f;
    const int I_[11] = {0,2,0,1,1,2, 0,1,2, 0,2};
    const int J_[11] = {2,0,1,0,2,1, 0,1,2, 0,2};
    const int K_[11] = {0,0,1,1,3,3, 2,2,2, 4,4};
    const float V_[11] = {A,A,A,A,A,A, -Bc,B2,-Bc, -A,A};
    for (int idx = lane; idx < 592; idx += 64) {
      float t = 0.0f;
      if (idx < 32)       { t = x[idx] * 0.1336306209562122f; }
      else if (idx < 128) { int j = idx-32,  u=j/3, k=j-u*3; t = x[u]*sh[1+k] * 0.1178511301977579f; }
      else if (idx < 288) { int j = idx-128, u=j/5, k=j-u*5; t = x[u]*sh[4+k] * 0.125f; }
      else if (idx < 336) { int j = idx-288, u=j/3, k=j-u*3; t = x[32+u*3+k] * 0.1178511301977579f; }
      else if (idx < 352) { int u = idx-336;
        t = (x[32+u*3]*sh[1] + x[32+u*3+1]*sh[2] + x[32+u*3+2]*sh[3]) * 0.0771516749810460f; }
      else if (idx < 432) { int j = idx-352, u=j/5, k=j-u*5;
        float s = 0.f;
        #pragma unroll
        for (int q = 0; q < 11; ++q) if (K_[q] == k)
          s += V_[q]*x[32+u*3+I_[q]]*sh[1+J_[q]];
        t = s * 0.2795084971874737f; }
      else if (idx < 480) { int j = idx-432, u=j/3, k=j-u*3;
        float s = 0.f;
        #pragma unroll
        for (int q = 0; q < 11; ++q) if (J_[q] == k)
          s += V_[q]*x[32+u*3+I_[q]]*sh[4+K_[q]];
        t = s * 0.2041241452319315f; }
      else if (idx < 520) { int j = idx-480, u=j/5, k=j-u*5; t = x[80+u*5+k] * 0.125f; }
      else if (idx < 544) { int j = idx-520, u=j/3, k=j-u*3;
        float s = 0.f;
        #pragma unroll
        for (int q = 0; q < 11; ++q) if (J_[q] == k)
          s += V_[q]*x[80+u*5+K_[q]]*sh[1+I_[q]];
        t = s * 0.2041241452319315f; }
      else if (idx < 552) { int u = idx-544;
        float s = 0.f;
        #pragma unroll
        for (int q = 0; q < 5; ++q) s += x[80+u*5+q]*sh[4+q];
        t = s * 0.0597614304667197f; }
      else { int j = idx-552, u=j/5, k=j-u*5;
        const float P = 0.2390457218668787f, Q = 0.2070196678027063f, R = 0.1195228609334394f;
        const int I2_[25] = {0,0,2, 0,0,1,1,3,3, 1,1,2, 1,1,4, 2, 2,3,3, 2,4,4, 3,3,4};
        const int J2_[25] = {0,2,0, 1,3,0,3,0,1, 1,2,1, 1,4,1, 2, 3,2,3, 4,2,4, 3,4,3};
        const int K2_[25] = {2,0,0, 3,1,3,0,1,0, 2,1,1, 4,1,1, 2, 3,3,2, 4,4,2, 4,3,3};
        const float V2_[25] = {P,P,P, -Q,-Q,-Q,-Q,-Q,-Q, -R,-R,-R, Q,Q,Q, -P,
                               -R,-R,-R, P,P,P, -Q,-Q,-Q};
        float s = 0.f;
        #pragma unroll
        for (int q = 0; q < 25; ++q) if (K2_[q] == k)
          s += V2_[q]*x[80+u*5+I2_[q]]*sh[4+J2_[q]];
        t = s * 0.2795084971874737f; }
      tl[wv][idx] = t;
    }
  }
  __syncthreads();

  const short* wrow = (const short*)wch + (size_t)el*3456;
  const float* t = tl[wv];
  float r0 = 0.f, r1 = 0.f, r2 = 0.f;
  #define PATHC(OFF, M1C, NKC, TOFFC, REG)                                  \
    { int v = lane / (NKC), k = lane - v*(NKC);                             \
      const short* wp = wrow + (OFF) + v*(M1C);                             \
      _Pragma("unroll")                                                     \
      for (int ub = 0; ub < (M1C)/8; ++ub) {                                \
        short8 w8 = *(const short8*)(wp + ub*8);                            \
        _Pragma("unroll")                                                   \
        for (int r = 0; r < 8; ++r)                                         \
          REG += us2f((unsigned short)w8[r]) * t[(TOFFC)+(ub*8+r)*(NKC)+k]; \
      } }
  if (lane < 32) {
    PATHC(0,    32, 1, 0,   r0)
    PATHC(2048, 16, 1, 336, r0)
    PATHC(3136,  8, 1, 544, r0)
  }
  if (lane < 48) {
    PATHC(1024, 32, 3, 32,  r1)
    PATHC(1792, 16, 3, 288, r1)
    PATHC(2688, 16, 3, 432, r1)
    PATHC(3008,  8, 3, 520, r1)
  }
  if (lane < 40) {
    PATHC(1536, 32, 5, 128, r2)
    PATHC(2560, 16, 5, 352, r2)
    PATHC(2944,  8, 5, 480, r2)
    PATHC(3392,  8, 5, 552, r2)
  }
  #undef PATHC

  if (live) {
    const float s = 0.3162277660168379f;
    float* mp = msg1 + (size_t)eg*120;
    if (lane < 32) mp[lane] = r0*s;
    if (lane < 48) mp[32 + lane] = r1*s;
    if (lane < 40) mp[80 + lane] = r2*s;
  }
}

// ================= output: dst-CSR msg1 aggregation + self-connection =================
__global__ void k_out(const float* __restrict__ msg1,
                      const int* __restrict__ start2, const int* __restrict__ perm2,
                      const float* __restrict__ node1,
                      const float* __restrict__ sc0e, const float* __restrict__ sc1o,
                      const float* __restrict__ sc2e, float* __restrict__ out) {
  __shared__ float x[120];
  int n = blockIdx.x, tid = threadIdx.x;
  if (tid < 120) x[tid] = node1[(size_t)n*120 + tid];
  __syncthreads();
  if (tid >= 120) return;
  float v = 0.f;
  const int s0 = start2[n], s1 = start2[n+1];
  for (int idx = s0; idx < s1; ++idx)
    v += msg1[(size_t)perm2[idx]*120 + tid];
  if (tid < 32) {
    float s = 0.f;
    for (int u = 0; u < 32; ++u) s += x[u]*sc0e[u*32 + tid];
    v += s * 0.1767766952966369f;
  } else if (tid < 80) {
    int jj = tid - 32, vv = jj/3, k = jj - vv*3;
    float s = 0.f;
    for (int u = 0; u < 16; ++u) s += x[32 + u*3 + k]*sc1o[u*16 + vv];
    v += s * 0.25f;
  } else {
    int jj = tid - 80, vv = jj/5, k = jj - vv*5;
    float s = 0.f;
    for (int u = 0; u < 8; ++u) s += x[80 + u*5 + k]*sc2e[u*8 + vv];
    v += s * 0.3535533905932738f;
  }
  out[(size_t)n*120 + tid] = v;
}

// ---------------- launch ----------------
extern "C" void kernel_launch(void* const* d_in, const int* in_sizes, int n_in,
                              void* d_out, int out_size, void* d_ws, size_t ws_size,
                              hipStream_t stream) {
  const float* embed   = (const float*)d_in[1];
  const float* rad_w1  = (const float*)d_in[2];
  const float* rad_b1  = (const float*)d_in[3];
  const float* rad_w2  = (const float*)d_in[4];
  const float* rad_b2  = (const float*)d_in[5];
  const float* wnn0_w1 = (const float*)d_in[6];
  const float* wnn0_w2 = (const float*)d_in[7];
  const float* wnn1_w1 = (const float*)d_in[8];
  const float* wnn1_w2 = (const float*)d_in[9];
  const float* sc0_0e  = (const float*)d_in[10];
  const float* sc1_0e  = (const float*)d_in[11];
  const float* sc1_1o  = (const float*)d_in[12];
  const float* sc1_2e  = (const float*)d_in[13];
  const float* edge_vec = (const float*)d_in[14];
  const float* edge_len = (const float*)d_in[15];
  const int*  anum    = (const int*)d_in[16];
  const int*  ei      = (const int*)d_in[17];

  float* ws = (float*)d_ws;
  float* shbuf = ws;                        // 600000
  float* bc    = ws + 600000;               // 400000
  bf16*  q1b   = (bf16*)(ws + 1000000);     // 1.6M f-slots
  float* node0 = ws + 2600000;              // 320000
  bf16*  node0b= (bf16*)(ws + 2920000);     // 160000 f-slots
  bf16*  W0rtb = (bf16*)(ws + 3080000);     // 114688 f-slots
  bf16*  W2t   = (bf16*)(ws + 3194688);     // 110592 f-slots
  bf16*  Mbb   = (bf16*)(ws + 3305280);     // 4096 f-slots
  float* bias0 = ws + 3309376;              // 64
  float* bias1 = ws + 3309440;              // 64
  int*   hist   = (int*)(ws + 3309504);     // 5000 (memset covers hist..cursor2)
  int*   cursor = (int*)(ws + 3314504);     // 5000
  int*   hist2  = (int*)(ws + 3319504);     // 5000
  int*   cursor2= (int*)(ws + 3324504);     // 5000
  int*   start  = (int*)(ws + 3329504);     // 5008
  int*   start2 = (int*)(ws + 3334512);     // 5008
  int*   perm   = (int*)(ws + 3339520);     // 50000
  int*   perm2  = (int*)(ws + 3389520);     // 50000
  float* node1 = ws + 3439520;              // 600000
  float* msg1  = ws + 4039520;              // 6000000 (50000 x 120)
  // dead-after-layer-0 region (wbuf aliases from q0 onward):
  float* q0    = ws + 10039520;             // 3200000
  float* zbuf  = ws + 13239520;             // 2800000 (50000 x 56)
  bf16*  G0    = (bf16*)(ws + 16039520);    // 17.92M bf16 -> end 24999520 (100 MB)
  bf16*  wbuf  = (bf16*)(ws + 10039520);    // aliases q0+zbuf+G0 (+beyond), layer-1 only

  // CH=25000: wbuf = 43.2M f-slots -> end 53239520 slots (213 MB); hot set ~208 MB < L3
  long long CH;
  if      (ws_size >= (10039520ull + 43200000ull)*4) CH = 25000;
  else if (ws_size >= (10039520ull + 21600000ull)*4) CH = 12500;
  else                                               CH = 6250;

  hipMemsetAsync(hist, 0, 20000*sizeof(int), stream);   // hist, cursor, hist2, cursor2

  k_setup<<<3222, 256, 0, stream>>>(edge_vec, edge_len, shbuf, bc,
                                    rad_w2, rad_b2, wnn0_w1, wnn1_w1, Mbb, bias0, bias1,
                                    embed, anum, node0, node0b,
                                    wnn0_w2, W0rtb, wnn1_w2, W2t, ei, hist, hist2);
  k_mid<<<1565, 256, 0, stream>>>(bc, rad_w1, rad_b1, Mbb, bias0, bias1,
                                  q0, q1b, hist, start, hist2, start2);
  k_pre0<<<196 + 14*157, 256, 0, stream>>>(ei, start, cursor, perm,
                                           start2, cursor2, perm2,
                                           node0b, W0rtb, G0);
  k_msg0z<<<NN, 256, 0, stream>>>(q0, G0, start, perm, zbuf);
  k_agg0<<<NN, 128, 0, stream>>>(zbuf, shbuf, start2, perm2, node0, sc0_0e, node1);

  for (long long e0 = 0; e0 < E_EDGES; e0 += CH) {
    k_bgemm<<<dim3(14, (unsigned)((CH+31)/32), 1), 256, 0, stream>>>(q1b, W2t, wbuf, 3456, 54, (int)e0, (int)CH);
    k_tp4<<<(unsigned)((CH+3)/4), 256, 0, stream>>>(wbuf, node1, shbuf, ei, (int)e0, (int)CH, msg1);
  }
  k_out<<<NN, 128, 0, stream>>>(msg1, start2, perm2, node1, sc1_0e, sc1_1o, sc1_2e, (float*)d_out);
}